// Round 8
// baseline (216.583 us; speedup 1.0000x reference)
//
#include <hip/hip_runtime.h>
#include <stdint.h>

typedef __attribute__((ext_vector_type(4)))  int   i32x4;
typedef __attribute__((ext_vector_type(8)))  int   i32x8;
typedef __attribute__((ext_vector_type(16))) float f32x16;

#define NB 8
#define NC 1024
#define NHW 3136
#define ROWB8 3200        // fp8 row stride: 3136 data + 64 zero pad = 25*128

__device__ inline float sq4(float4 v){
  return fmaf(v.x,v.x, fmaf(v.y,v.y, fmaf(v.z,v.z, v.w*v.w)));
}

__device__ __forceinline__ void load_lds16(const void* g, void* l){
  __builtin_amdgcn_global_load_lds(
      (const __attribute__((address_space(1))) unsigned int*)g,
      (__attribute__((address_space(3))) unsigned int*)l,
      16, 0, 0);
}

// MX-scaled fp8 MFMA, both formats e4m3 (fmt=0), all block scales = 2^0.
__device__ __forceinline__ f32x16 MFS(i32x8 a, i32x8 b, f32x16 c){
  return __builtin_amdgcn_mfma_scale_f32_32x32x64_f8f6f4(
      a, b, c, 0, 0, 0, 0x7F7F7F7F, 0, 0x7F7F7F7F);
}

__device__ __forceinline__ i32x8 rdfrag(const char* base, int cLo, int cHi){
  i32x4 lo = *(const i32x4*)(base + cLo);
  i32x4 hi = *(const i32x4*)(base + cHi);
  return __builtin_shufflevector(lo, hi, 0,1,2,3,4,5,6,7);
}

__device__ __forceinline__ int cvt4(float4 v, float s){
  int pk = __builtin_amdgcn_cvt_pk_fp8_f32(v.x*s, v.y*s, 0,  0);
  pk     = __builtin_amdgcn_cvt_pk_fp8_f32(v.z*s, v.w*s, pk, 1);
  return pk;
}

// wave-level row normalize (verified r6/r7): 13 float4 loads, 6x shfl_xor
// butterfly, cvt to e4m3 pre-scaled by 32, + 64 B zero pad.
__device__ __forceinline__ void loadRow(const float* src, int l, float4* v){
  const float4* p = (const float4*)src;
  #pragma unroll
  for (int j = 0; j < 12; j++) v[j] = p[l + 64*j];
  v[12] = (l < 16) ? p[768 + l] : make_float4(0.f,0.f,0.f,0.f);
}
__device__ __forceinline__ void finRow(const float4* v, char* dst, int l){
  float ssq = 0.f;
  #pragma unroll
  for (int j = 0; j < 13; j++) ssq += sq4(v[j]);
  #pragma unroll
  for (int off = 32; off; off >>= 1) ssq += __shfl_xor(ssq, off);
  const float inv = 32.0f / fmaxf(sqrtf(ssq), 1e-12f);
  #pragma unroll
  for (int j = 0; j < 12; j++)
    *(int*)(dst + 4*(l + 64*j)) = cvt4(v[j], inv);
  if (l < 16)      *(int*)(dst + 3072 + 4*l) = cvt4(v[12], inv);
  else if (l < 20) *(int4*)(dst + 3136 + 16*(l-16)) = make_int4(0,0,0,0);
}

__global__ void k_zero(int* w){
  if (threadIdx.x < 16) w[threadIdx.x] = 0;   // acc[2] + cnt[8] + done
}

#define BAR   __builtin_amdgcn_s_barrier()
#define LGKM0 asm volatile("s_waitcnt lgkmcnt(0)" ::: "memory")
#define LGKM8 asm volatile("s_waitcnt lgkmcnt(8)" ::: "memory")
#define VM6   asm volatile("s_waitcnt vmcnt(6)" ::: "memory")
#define SB0   __builtin_amdgcn_sched_barrier(0)
#define PRIO1 __builtin_amdgcn_s_setprio(1)
#define PRIO0 __builtin_amdgcn_s_setprio(0)

#define ISSUE(MAT, D, H, KT) do{ \
  const char* _g = ((MAT)? gB : gA) + (KT)*128 + (H)*(128*ROWB8); \
  char* _d = ldsw + (D)*65536 + (MAT)*32768 + (H)*16384; \
  load_lds16(_g,              _d); \
  load_lds16(_g + 64*ROWB8,   _d + 8192); \
}while(0)

#define RDA(D, MH) do{ \
  const char* _a = aRow + (D) + (MH)*8192; \
  af[0][0] = rdfrag(_a,        c00, c01); \
  af[0][1] = rdfrag(_a,        c10, c11); \
  af[1][0] = rdfrag(_a + 4096, c00, c01); \
  af[1][1] = rdfrag(_a + 4096, c10, c11); \
}while(0)

#define RDB(D, NH) do{ \
  const char* _b = bRow + (D) + (NH)*4096; \
  bf[NH][0] = rdfrag(_b, c00, c01); \
  bf[NH][1] = rdfrag(_b, c10, c11); \
}while(0)

#define MMQ(MH, NH) do{ \
  acc[((MH)*2+0)*2+(NH)] = MFS(af[0][0], bf[NH][0], acc[((MH)*2+0)*2+(NH)]); \
  acc[((MH)*2+1)*2+(NH)] = MFS(af[1][0], bf[NH][0], acc[((MH)*2+1)*2+(NH)]); \
  acc[((MH)*2+0)*2+(NH)] = MFS(af[0][1], bf[NH][1], acc[((MH)*2+0)*2+(NH)]); \
  acc[((MH)*2+1)*2+(NH)] = MFS(af[1][1], bf[NH][1], acc[((MH)*2+1)*2+(NH)]); \
}while(0)

// ---------------- fused norm + 8-phase MX-fp8 GEMM, batch-pipelined --------
// Grid 256 x 512. 128 KiB LDS forces exactly 1 block/CU -> all blocks
// co-resident (spin-safe). Norm sweeps batches 0..7; for batch b only
// blocks with gemm job-batch >= b participate (P_b = 256-26b), so every
// batch's rows are produced strictly before any of its consumers spin.
// Publication: vmcnt-drained stores (syncthreads) + threadfence (L2 wb) +
// release-agent atomicAdd of the row count; consumer spins relaxed-agent,
// final acquire load (L2 inv), syncthreads, then runs the verified r4
// gemm schedule unchanged. Finalizer folded in via done-counter (r7).
__global__ __launch_bounds__(512,2) void k_fused(const float* __restrict__ s,
                                                 const float* __restrict__ t,
                                                 char* __restrict__ Sn,
                                                 char* __restrict__ Tn,
                                                 float* __restrict__ accbuf,
                                                 float* __restrict__ out){
  __shared__ char lds[131072];
  const int i   = blockIdx.x;          // 0..255
  const int tid = threadIdx.x;
  const int l   = tid & 63;
  const int wv  = tid >> 6;
  int* cnt  = (int*)accbuf + 4;        // cnt[0..7]
  int* done = (int*)accbuf + 12;

  const int jb = (i < 208) ? (i & 7) : 7;   // norm participation bound
  // ---------------- norm phase ----------------
  for (int b = 0; b <= jb; b++){
    const int P = 256 - 26*b;
    int r;
    if (i < 208){
      const int res = i & 7;
      r = (i >> 3)*(8 - b) + (res > b ? res - b : 0);
    } else {
      r = 26*(8 - b) + (i - 208);
    }
    const int start = (r*2048)/P;
    const int end   = ((r+1)*2048)/P;
    for (int idx = start + wv; idx < end; idx += 8){
      const int off = idx & 1023;
      const bool isS = (idx < 1024);
      const int gr = b*1024 + off;
      const float* src = (isS ? s : t) + (size_t)gr * NHW;
      char*        dst = (isS ? Sn : Tn) + (size_t)gr * ROWB8;
      float4 v[13];
      loadRow(src, l, v);
      finRow(v, dst, l);
    }
    __syncthreads();                    // all waves' stores drained (vmcnt0)
    if (tid == 0){
      __threadfence();                  // L2 writeback (agent release)
      __hip_atomic_fetch_add(&cnt[b], end - start,
                             __ATOMIC_RELEASE, __HIP_MEMORY_SCOPE_AGENT);
    }
  }
  if (i >= 208) return;                 // helpers done

  // ---------------- wait for this job's batch ----------------
  if (tid == 0){
    while (__hip_atomic_load(&cnt[jb], __ATOMIC_RELAXED,
                             __HIP_MEMORY_SCOPE_AGENT) < 2048)
      __builtin_amdgcn_s_sleep(8);
    (void)__hip_atomic_load(&cnt[jb], __ATOMIC_ACQUIRE,
                            __HIP_MEMORY_SCOPE_AGENT);
  }
  __syncthreads();

  // ---------------- gemm (r4-verified schedule, b = jb) ----------------
  const int w   = wv;
  const int wr  = w >> 2;
  const int wc  = w & 3;
  const int idx = i >> 3;              // 0..25
  int tm, tn, which; float wgt;
  if (idx < 16){ which = 1; tm = idx >> 2; tn = idx & 3; wgt = 1.f; }
  else {
    int e = idx - 16; which = 0;
    if      (e < 4){ tm = 0; tn = e;   }
    else if (e < 7){ tm = 1; tn = e-3; }
    else if (e < 9){ tm = 2; tn = e-5; }
    else           { tm = 3; tn = 3;   }
    wgt = (tm == tn) ? 1.f : 2.f;
  }
  const char* Ab = (which ? Tn : Sn) + (size_t)jb*(NC*ROWB8) + (size_t)tm*(256*ROWB8);
  const char* Bb = Sn                + (size_t)jb*(NC*ROWB8) + (size_t)tn*(256*ROWB8);

  const int scol = ((l & 7) << 4) ^ ((l >> 3) << 4);
  const char* gA = Ab + (8*w + (l >> 3))*ROWB8 + scol;
  const char* gB = Bb + (8*w + (l >> 3))*ROWB8 + scol;
  char* ldsw = lds + w*1024;

  const int swz = (l & 7) << 4;
  const int cg  = 32*(l >> 5);
  const int c00 = ( cg           ) ^ swz;
  const int c01 = ( cg | 16      ) ^ swz;
  const int c10 = ( cg | 64      ) ^ swz;
  const int c11 = ( cg | 64 | 16 ) ^ swz;
  const char* aRow = lds +         (wr*128 + (l & 31))*128;
  const char* bRow = lds + 32768 + (wc*64  + (l & 31))*128;

  i32x8 af[2][2], bf[2][2];
  f32x16 acc[8];
  #pragma unroll
  for (int k = 0; k < 8; k++) acc[k] = (f32x16){};

  ISSUE(1,0,0,0); ISSUE(1,0,1,0); ISSUE(0,0,0,0); ISSUE(0,0,1,0);
  ISSUE(1,1,0,1); ISSUE(1,1,1,1); ISSUE(0,1,0,1);
  VM6; BAR;   // oldest 8 loads (= all of t0) landed

  for (int it = 0; it < 12; it++){
    const int t1 = 2*it + 1;
    const int t2 = 2*it + 2;
    int t3 = 2*it + 3; if (t3 > 24) t3 = 24;   // clamp keeps vmcnt uniform

    // ---- tile 2it (buf0) ----
    RDA(0,0); RDB(0,0);
    ISSUE(0,1,1,t1);
    LGKM8; BAR; LGKM0; SB0; PRIO1; MMQ(0,0); PRIO0; BAR;
    RDB(0,1);
    BAR; LGKM0; SB0; PRIO1; MMQ(0,1); PRIO0; BAR;
    RDA(0,1);
    ISSUE(1,0,0,t2); ISSUE(1,0,1,t2);
    BAR; LGKM0; SB0; PRIO1; MMQ(1,0); PRIO0; BAR;
    ISSUE(0,0,0,t2);
    BAR; PRIO1; MMQ(1,1); PRIO0; VM6; BAR;

    // ---- tile 2it+1 (buf1) ----
    RDA(65536,0); RDB(65536,0);
    ISSUE(0,0,1,t2);
    LGKM8; BAR; LGKM0; SB0; PRIO1; MMQ(0,0); PRIO0; BAR;
    RDB(65536,1);
    BAR; LGKM0; SB0; PRIO1; MMQ(0,1); PRIO0; BAR;
    RDA(65536,1);
    ISSUE(1,1,0,t3); ISSUE(1,1,1,t3);
    BAR; LGKM0; SB0; PRIO1; MMQ(1,0); PRIO0; BAR;
    ISSUE(0,1,0,t3);
    BAR; PRIO1; MMQ(1,1); PRIO0; VM6; BAR;
  }

  // Epilogue: tile 24 (buf0), fully landed by final VM6+BAR.
  RDA(0,0); RDB(0,0); RDB(0,1);
  MMQ(0,0); MMQ(0,1);
  RDA(0,1);
  MMQ(1,0); MMQ(1,1);

  // Fused reduction: sum of squares of the 256x256 tile (layout-free).
  float p = 0.f;
  #pragma unroll
  for (int f = 0; f < 8; f++)
    #pragma unroll
    for (int e = 0; e < 16; e++)
      p = fmaf(acc[f][e], acc[f][e], p);
  #pragma unroll
  for (int off = 32; off; off >>= 1) p += __shfl_down(p, off);
  __syncthreads();
  float* red = (float*)lds;
  if (l == 0) red[w] = p;
  __syncthreads();
  if (tid == 0){
    float sum = red[0]+red[1]+red[2]+red[3]+red[4]+red[5]+red[6]+red[7];
    atomicAdd(&accbuf[which], wgt * sum);
    __threadfence();                                   // adds visible before count
    int old = atomicAdd(done, 1);
    if (old == 207){                                   // last job finalizes
      float a0 = atomicAdd(&accbuf[0], 0.f);           // coherent reads
      float a1 = atomicAdd(&accbuf[1], 0.f);
      // / (8*1024*1024) and / 2^20 (both operands pre-scaled by 2^5)
      out[0] = (a0 - 2.0f*a1) * 1.1368683772161603e-13f;   // 2^-43
    }
  }
}

extern "C" void kernel_launch(void* const* d_in, const int* in_sizes, int n_in,
                              void* d_out, int out_size, void* d_ws, size_t ws_size,
                              hipStream_t stream){
  const float* fs = (const float*)d_in[0];
  const float* ft = (const float*)d_in[1];
  float* out = (float*)d_out;
  float* accbuf = (float*)d_ws;
  char* Sn = (char*)d_ws + 256;
  char* Tn = Sn + (size_t)NB*NC*ROWB8;   // 2 x 26.2 MB of ws

  k_zero<<<1, 64, 0, stream>>>((int*)d_ws);
  k_fused<<<dim3(256), dim3(512), 0, stream>>>(fs, ft, Sn, Tn, accbuf, out);
}

// Round 9
// 87.160 us; speedup vs baseline: 2.4849x; 2.4849x over previous
//
#include <hip/hip_runtime.h>
#include <stdint.h>

typedef __attribute__((ext_vector_type(4)))  int   i32x4;
typedef __attribute__((ext_vector_type(8)))  int   i32x8;
typedef __attribute__((ext_vector_type(16))) float f32x16;

#define NB 8
#define NC 1024
#define NHW 3136
#define ROWB8 3200        // fp8 row stride: 3136 data + 64 zero pad = 25*128

__device__ inline float sq4(float4 v){
  return fmaf(v.x,v.x, fmaf(v.y,v.y, fmaf(v.z,v.z, v.w*v.w)));
}

__device__ __forceinline__ void load_lds16(const void* g, void* l){
  __builtin_amdgcn_global_load_lds(
      (const __attribute__((address_space(1))) unsigned int*)g,
      (__attribute__((address_space(3))) unsigned int*)l,
      16, 0, 0);
}

// MX-scaled fp8 MFMA, both formats e4m3 (fmt=0), all block scales = 2^0.
__device__ __forceinline__ f32x16 MFS(i32x8 a, i32x8 b, f32x16 c){
  return __builtin_amdgcn_mfma_scale_f32_32x32x64_f8f6f4(
      a, b, c, 0, 0, 0, 0x7F7F7F7F, 0, 0x7F7F7F7F);
}

__device__ __forceinline__ i32x8 rdfrag(const char* base, int cLo, int cHi){
  i32x4 lo = *(const i32x4*)(base + cLo);
  i32x4 hi = *(const i32x4*)(base + cHi);
  return __builtin_shufflevector(lo, hi, 0,1,2,3,4,5,6,7);
}

__device__ __forceinline__ int cvt4(float4 v, float s){
  int pk = __builtin_amdgcn_cvt_pk_fp8_f32(v.x*s, v.y*s, 0,  0);
  pk     = __builtin_amdgcn_cvt_pk_fp8_f32(v.z*s, v.w*s, pk, 1);
  return pk;
}

// ---------------- k_norm: TWO rows per 256-thread block ------------------
// All 8 float4 loads (both rows) issued as NAMED SCALARS before any use ->
// ~6.5-deep MLP per thread (2x r4's 3.25), no arrays (no scratch risk).
// One barrier; per-row block reduce via shfl + tiny LDS; e4m3 out with
// pre-scale 32 and 64 B zero pad. Block 0 zeroes the accumulators.
__global__ __launch_bounds__(256) void k_norm(const float* __restrict__ s,
                                              const float* __restrict__ t,
                                              char* __restrict__ Sn,
                                              char* __restrict__ Tn,
                                              float* __restrict__ accbuf){
  const int g   = blockIdx.x;              // 0..8191, two rows each
  const int tid = threadIdx.x;
  if (g == 0 && tid == 0){ accbuf[0] = 0.f; accbuf[1] = 0.f; }
  const bool isS = (g < 4096);
  const int r0 = (isS ? g : g - 4096) * 2;
  const float* src = (isS ? s : t) + (size_t)r0 * NHW;
  char*        dst = (isS ? Sn : Tn) + (size_t)r0 * ROWB8;
  const float4* p0 = (const float4*)src;        // 784 float4 per row
  const float4* p1 = (const float4*)(src + NHW);

  float4 a0 = p0[tid], a1 = p0[tid+256], a2 = p0[tid+512];
  float4 b0 = p1[tid], b1 = p1[tid+256], b2 = p1[tid+512];
  float4 a3 = make_float4(0.f,0.f,0.f,0.f);
  float4 b3 = make_float4(0.f,0.f,0.f,0.f);
  if (tid < 16){ a3 = p0[tid+768]; b3 = p1[tid+768]; }

  float sa = sq4(a0)+sq4(a1)+sq4(a2)+sq4(a3);
  float sb = sq4(b0)+sq4(b1)+sq4(b2)+sq4(b3);
  #pragma unroll
  for (int off = 32; off; off >>= 1){
    sa += __shfl_down(sa, off);
    sb += __shfl_down(sb, off);
  }
  __shared__ float redA[4], redB[4];
  if ((tid & 63) == 0){ redA[tid>>6] = sa; redB[tid>>6] = sb; }
  __syncthreads();
  const float invA = 32.0f / fmaxf(sqrtf(redA[0]+redA[1]+redA[2]+redA[3]), 1e-12f);
  const float invB = 32.0f / fmaxf(sqrtf(redB[0]+redB[1]+redB[2]+redB[3]), 1e-12f);

  char* d1 = dst + ROWB8;
  *(int*)(dst + 4*tid)       = cvt4(a0, invA);
  *(int*)(dst + 4*tid + 1024)= cvt4(a1, invA);
  *(int*)(dst + 4*tid + 2048)= cvt4(a2, invA);
  *(int*)(d1  + 4*tid)       = cvt4(b0, invB);
  *(int*)(d1  + 4*tid + 1024)= cvt4(b1, invB);
  *(int*)(d1  + 4*tid + 2048)= cvt4(b2, invB);
  if (tid < 16){
    *(int*)(dst + 3072 + 4*tid) = cvt4(a3, invA);
    *(int*)(d1  + 3072 + 4*tid) = cvt4(b3, invB);
  } else if (tid < 20){
    *(int4*)(dst + 3136 + 16*(tid-16)) = make_int4(0,0,0,0);
    *(int4*)(d1  + 3136 + 16*(tid-16)) = make_int4(0,0,0,0);
  }
}

// ---------------- 256x256 8-phase MX-fp8 GEMM, fused squared-sum -----------
// (byte-identical schedule to the r4-verified kernel)
// K-tile = 128 fp8 = 128 B per row. 8 waves 2(M)x4(N); per-wave 128x64 out =
// 4 m-frags x 2 n-frags of 32x32, acc[8] f32x16. Dots scaled by 2^10,
// squared sums by 2^20, divided out in k_fin.

#define BAR   __builtin_amdgcn_s_barrier()
#define LGKM0 asm volatile("s_waitcnt lgkmcnt(0)" ::: "memory")
#define LGKM8 asm volatile("s_waitcnt lgkmcnt(8)" ::: "memory")
#define VM6   asm volatile("s_waitcnt vmcnt(6)" ::: "memory")
#define SB0   __builtin_amdgcn_sched_barrier(0)
#define PRIO1 __builtin_amdgcn_s_setprio(1)
#define PRIO0 __builtin_amdgcn_s_setprio(0)

#define ISSUE(MAT, D, H, KT) do{ \
  const char* _g = ((MAT)? gB : gA) + (KT)*128 + (H)*(128*ROWB8); \
  char* _d = ldsw + (D)*65536 + (MAT)*32768 + (H)*16384; \
  load_lds16(_g,              _d); \
  load_lds16(_g + 64*ROWB8,   _d + 8192); \
}while(0)

#define RDA(D, MH) do{ \
  const char* _a = aRow + (D) + (MH)*8192; \
  af[0][0] = rdfrag(_a,        c00, c01); \
  af[0][1] = rdfrag(_a,        c10, c11); \
  af[1][0] = rdfrag(_a + 4096, c00, c01); \
  af[1][1] = rdfrag(_a + 4096, c10, c11); \
}while(0)

#define RDB(D, NH) do{ \
  const char* _b = bRow + (D) + (NH)*4096; \
  bf[NH][0] = rdfrag(_b, c00, c01); \
  bf[NH][1] = rdfrag(_b, c10, c11); \
}while(0)

#define MMQ(MH, NH) do{ \
  acc[((MH)*2+0)*2+(NH)] = MFS(af[0][0], bf[NH][0], acc[((MH)*2+0)*2+(NH)]); \
  acc[((MH)*2+1)*2+(NH)] = MFS(af[1][0], bf[NH][0], acc[((MH)*2+1)*2+(NH)]); \
  acc[((MH)*2+0)*2+(NH)] = MFS(af[0][1], bf[NH][1], acc[((MH)*2+0)*2+(NH)]); \
  acc[((MH)*2+1)*2+(NH)] = MFS(af[1][1], bf[NH][1], acc[((MH)*2+1)*2+(NH)]); \
}while(0)

__global__ __launch_bounds__(512,2) void k_gemm(const char* __restrict__ Sn,
                                                const char* __restrict__ Tn,
                                                float* __restrict__ accbuf){
  __shared__ char lds[131072];
  const int tid = threadIdx.x;
  const int l   = tid & 63;
  const int w   = tid >> 6;
  const int wr  = w >> 2;      // 0..1
  const int wc  = w & 3;       // 0..3

  const int b   = blockIdx.x & 7;    // batch -> XCD (208 = 8*26)
  const int idx = blockIdx.x >> 3;   // 0..25
  int tm, tn, which; float wgt;
  if (idx < 16){ which = 1; tm = idx >> 2; tn = idx & 3; wgt = 1.f; }
  else {
    int e = idx - 16; which = 0;
    if      (e < 4){ tm = 0; tn = e;   }
    else if (e < 7){ tm = 1; tn = e-3; }
    else if (e < 9){ tm = 2; tn = e-5; }
    else           { tm = 3; tn = 3;   }
    wgt = (tm == tn) ? 1.f : 2.f;
  }
  const char* Ab = (which ? Tn : Sn) + (size_t)b*(NC*ROWB8) + (size_t)tm*(256*ROWB8);
  const char* Bb = Sn                + (size_t)b*(NC*ROWB8) + (size_t)tn*(256*ROWB8);

  const int scol = ((l & 7) << 4) ^ ((l >> 3) << 4);
  const char* gA = Ab + (8*w + (l >> 3))*ROWB8 + scol;
  const char* gB = Bb + (8*w + (l >> 3))*ROWB8 + scol;
  char* ldsw = lds + w*1024;

  const int swz = (l & 7) << 4;
  const int cg  = 32*(l >> 5);
  const int c00 = ( cg           ) ^ swz;
  const int c01 = ( cg | 16      ) ^ swz;
  const int c10 = ( cg | 64      ) ^ swz;
  const int c11 = ( cg | 64 | 16 ) ^ swz;
  const char* aRow = lds +         (wr*128 + (l & 31))*128;
  const char* bRow = lds + 32768 + (wc*64  + (l & 31))*128;

  i32x8 af[2][2], bf[2][2];
  f32x16 acc[8];
  #pragma unroll
  for (int i = 0; i < 8; i++) acc[i] = (f32x16){};

  ISSUE(1,0,0,0); ISSUE(1,0,1,0); ISSUE(0,0,0,0); ISSUE(0,0,1,0);
  ISSUE(1,1,0,1); ISSUE(1,1,1,1); ISSUE(0,1,0,1);
  VM6; BAR;   // oldest 8 loads (= all of t0) landed

  for (int i = 0; i < 12; i++){
    const int t1 = 2*i + 1;
    const int t2 = 2*i + 2;
    int t3 = 2*i + 3; if (t3 > 24) t3 = 24;   // clamp keeps vmcnt uniform

    // ---- tile 2i (buf0) ----
    RDA(0,0); RDB(0,0);
    ISSUE(0,1,1,t1);
    LGKM8; BAR; LGKM0; SB0; PRIO1; MMQ(0,0); PRIO0; BAR;
    RDB(0,1);
    BAR; LGKM0; SB0; PRIO1; MMQ(0,1); PRIO0; BAR;
    RDA(0,1);
    ISSUE(1,0,0,t2); ISSUE(1,0,1,t2);
    BAR; LGKM0; SB0; PRIO1; MMQ(1,0); PRIO0; BAR;
    ISSUE(0,0,0,t2);
    BAR; PRIO1; MMQ(1,1); PRIO0; VM6; BAR;

    // ---- tile 2i+1 (buf1) ----
    RDA(65536,0); RDB(65536,0);
    ISSUE(0,0,1,t2);
    LGKM8; BAR; LGKM0; SB0; PRIO1; MMQ(0,0); PRIO0; BAR;
    RDB(65536,1);
    BAR; LGKM0; SB0; PRIO1; MMQ(0,1); PRIO0; BAR;
    RDA(65536,1);
    ISSUE(1,1,0,t3); ISSUE(1,1,1,t3);
    BAR; LGKM0; SB0; PRIO1; MMQ(1,0); PRIO0; BAR;
    ISSUE(0,1,0,t3);
    BAR; PRIO1; MMQ(1,1); PRIO0; VM6; BAR;
  }

  // Epilogue: tile 24 (buf0), fully landed by final VM6+BAR.
  RDA(0,0); RDB(0,0); RDB(0,1);
  MMQ(0,0); MMQ(0,1);
  RDA(0,1);
  MMQ(1,0); MMQ(1,1);

  // Fused reduction: sum of squares of the 256x256 tile (layout-free).
  float p = 0.f;
  #pragma unroll
  for (int f = 0; f < 8; f++)
    #pragma unroll
    for (int e = 0; e < 16; e++)
      p = fmaf(acc[f][e], acc[f][e], p);
  #pragma unroll
  for (int off = 32; off; off >>= 1) p += __shfl_down(p, off);
  __syncthreads();
  float* red = (float*)lds;
  if (l == 0) red[w] = p;
  __syncthreads();
  if (tid == 0){
    float sum = red[0]+red[1]+red[2]+red[3]+red[4]+red[5]+red[6]+red[7];
    atomicAdd(&accbuf[which], wgt * sum);
  }
}

__global__ void k_fin(const float* __restrict__ acc, float* __restrict__ out){
  // / (8*1024*1024) and / 2^20 (both operands pre-scaled by 2^5)
  out[0] = (acc[0] - 2.0f*acc[1]) * 1.1368683772161603e-13f;   // 2^-43
}

extern "C" void kernel_launch(void* const* d_in, const int* in_sizes, int n_in,
                              void* d_out, int out_size, void* d_ws, size_t ws_size,
                              hipStream_t stream){
  const float* fs = (const float*)d_in[0];
  const float* ft = (const float*)d_in[1];
  float* out = (float*)d_out;
  float* accbuf = (float*)d_ws;
  char* Sn = (char*)d_ws + 256;
  char* Tn = Sn + (size_t)NB*NC*ROWB8;   // 2 x 26.2 MB of ws

  k_norm<<<dim3(8192), dim3(256), 0, stream>>>(fs, ft, Sn, Tn, accbuf);
  k_gemm<<<dim3(208), dim3(512), 0, stream>>>(Sn, Tn, accbuf);
  k_fin<<<1, 1, 0, stream>>>(accbuf, out);
}

// Round 10
// 85.473 us; speedup vs baseline: 2.5339x; 1.0197x over previous
//
#include <hip/hip_runtime.h>
#include <stdint.h>

typedef __attribute__((ext_vector_type(4)))  int   i32x4;
typedef __attribute__((ext_vector_type(8)))  int   i32x8;
typedef __attribute__((ext_vector_type(16))) float f32x16;

#define NB 8
#define NC 1024
#define NHW 3136
#define ROWB8 3200        // fp8 row stride: 3136 data + 64 zero pad = 25*128

__device__ inline float sq4(float4 v){
  return fmaf(v.x,v.x, fmaf(v.y,v.y, fmaf(v.z,v.z, v.w*v.w)));
}

__device__ __forceinline__ void load_lds16(const void* g, void* l){
  __builtin_amdgcn_global_load_lds(
      (const __attribute__((address_space(1))) unsigned int*)g,
      (__attribute__((address_space(3))) unsigned int*)l,
      16, 0, 0);
}

// MX-scaled fp8 MFMA, both formats e4m3 (fmt=0), all block scales = 2^0.
__device__ __forceinline__ f32x16 MFS(i32x8 a, i32x8 b, f32x16 c){
  return __builtin_amdgcn_mfma_scale_f32_32x32x64_f8f6f4(
      a, b, c, 0, 0, 0, 0x7F7F7F7F, 0, 0x7F7F7F7F);
}

__device__ __forceinline__ i32x8 rdfrag(const char* base, int cLo, int cHi){
  i32x4 lo = *(const i32x4*)(base + cLo);
  i32x4 hi = *(const i32x4*)(base + cHi);
  return __builtin_shufflevector(lo, hi, 0,1,2,3,4,5,6,7);
}

__device__ __forceinline__ int cvt4(float4 v, float s){
  int pk = __builtin_amdgcn_cvt_pk_fp8_f32(v.x*s, v.y*s, 0,  0);
  pk     = __builtin_amdgcn_cvt_pk_fp8_f32(v.z*s, v.w*s, pk, 1);
  return pk;
}

// ---------------- k_norm: LDS-staged via global_load_lds DMA ---------------
// One row (3136 fp32 = 12544 B) per 256-thread block. The row is DMA'd into
// LDS (3 full rounds + 16-lane tail; wave-uniform dest + lane*16), then both
// the reduction read AND the post-barrier cvt re-read come from LDS --
// sidestepping hipcc's reload-over-retention choice that made r4/r6/r9 pay
// an L2/HBM reread after the barrier. VGPR stays ~24; 12.6 KB LDS -> 8
// blocks/CU (32 waves). Output: e4m3 pre-scaled by 32, + 64 B zero pad.
__global__ __launch_bounds__(256, 8) void k_norm(const float* __restrict__ s,
                                                 const float* __restrict__ t,
                                                 char* __restrict__ Sn,
                                                 char* __restrict__ Tn,
                                                 float* __restrict__ accbuf){
  __shared__ float4 buf[784];          // 12544 B
  __shared__ float red[4];
  const int g   = blockIdx.x;          // one row per block, 16384 rows
  const int tid = threadIdx.x;
  if (g == 0 && tid == 0){ accbuf[0] = 0.f; accbuf[1] = 0.f; }
  const bool isS = (g < 8192);
  const int r = isS ? g : g - 8192;
  const float* src = (isS ? s : t) + (size_t)r * NHW;
  char*        dst = (isS ? Sn : Tn) + (size_t)r * ROWB8;

  // DMA row -> LDS (no VGPR round-trip)
  {
    const char* gp = (const char*)src + tid*16;
    char*       lp = (char*)buf + tid*16;     // wave-uniform base + lane*16
    load_lds16(gp,         lp);
    load_lds16(gp +  4096, lp +  4096);
    load_lds16(gp +  8192, lp +  8192);
    if (tid < 16) load_lds16(gp + 12288, lp + 12288);
  }
  asm volatile("s_waitcnt vmcnt(0)" ::: "memory");
  __syncthreads();

  // reduce from LDS
  float ssq = sq4(buf[tid]) + sq4(buf[tid+256]) + sq4(buf[tid+512]);
  if (tid < 16) ssq += sq4(buf[tid+768]);
  #pragma unroll
  for (int off = 32; off; off >>= 1) ssq += __shfl_down(ssq, off);
  if ((tid & 63) == 0) red[tid>>6] = ssq;
  __syncthreads();
  const float inv = 32.0f / fmaxf(sqrtf(red[0]+red[1]+red[2]+red[3]), 1e-12f);

  // cvt+store; re-read is from LDS (cheap), not L2/HBM
  *(int*)(dst + 4*tid)        = cvt4(buf[tid],     inv);
  *(int*)(dst + 4*tid + 1024) = cvt4(buf[tid+256], inv);
  *(int*)(dst + 4*tid + 2048) = cvt4(buf[tid+512], inv);
  if (tid < 16)      *(int*)(dst + 3072 + 4*tid) = cvt4(buf[tid+768], inv);
  else if (tid < 20) *(int4*)(dst + 3136 + 16*(tid-16)) = make_int4(0,0,0,0);
}

// ---------------- 256x256 8-phase MX-fp8 GEMM, fused squared-sum -----------
// (byte-identical schedule to the r4-verified kernel)
// K-tile = 128 fp8 = 128 B per row. 8 waves 2(M)x4(N); per-wave 128x64 out =
// 4 m-frags x 2 n-frags of 32x32, acc[8] f32x16. Dots scaled by 2^10,
// squared sums by 2^20, divided out in k_fin.

#define BAR   __builtin_amdgcn_s_barrier()
#define LGKM0 asm volatile("s_waitcnt lgkmcnt(0)" ::: "memory")
#define LGKM8 asm volatile("s_waitcnt lgkmcnt(8)" ::: "memory")
#define VM6   asm volatile("s_waitcnt vmcnt(6)" ::: "memory")
#define SB0   __builtin_amdgcn_sched_barrier(0)
#define PRIO1 __builtin_amdgcn_s_setprio(1)
#define PRIO0 __builtin_amdgcn_s_setprio(0)

#define ISSUE(MAT, D, H, KT) do{ \
  const char* _g = ((MAT)? gB : gA) + (KT)*128 + (H)*(128*ROWB8); \
  char* _d = ldsw + (D)*65536 + (MAT)*32768 + (H)*16384; \
  load_lds16(_g,              _d); \
  load_lds16(_g + 64*ROWB8,   _d + 8192); \
}while(0)

#define RDA(D, MH) do{ \
  const char* _a = aRow + (D) + (MH)*8192; \
  af[0][0] = rdfrag(_a,        c00, c01); \
  af[0][1] = rdfrag(_a,        c10, c11); \
  af[1][0] = rdfrag(_a + 4096, c00, c01); \
  af[1][1] = rdfrag(_a + 4096, c10, c11); \
}while(0)

#define RDB(D, NH) do{ \
  const char* _b = bRow + (D) + (NH)*4096; \
  bf[NH][0] = rdfrag(_b, c00, c01); \
  bf[NH][1] = rdfrag(_b, c10, c11); \
}while(0)

#define MMQ(MH, NH) do{ \
  acc[((MH)*2+0)*2+(NH)] = MFS(af[0][0], bf[NH][0], acc[((MH)*2+0)*2+(NH)]); \
  acc[((MH)*2+1)*2+(NH)] = MFS(af[1][0], bf[NH][0], acc[((MH)*2+1)*2+(NH)]); \
  acc[((MH)*2+0)*2+(NH)] = MFS(af[0][1], bf[NH][1], acc[((MH)*2+0)*2+(NH)]); \
  acc[((MH)*2+1)*2+(NH)] = MFS(af[1][1], bf[NH][1], acc[((MH)*2+1)*2+(NH)]); \
}while(0)

__global__ __launch_bounds__(512,2) void k_gemm(const char* __restrict__ Sn,
                                                const char* __restrict__ Tn,
                                                float* __restrict__ accbuf){
  __shared__ char lds[131072];
  const int tid = threadIdx.x;
  const int l   = tid & 63;
  const int w   = tid >> 6;
  const int wr  = w >> 2;      // 0..1
  const int wc  = w & 3;       // 0..3

  const int b   = blockIdx.x & 7;    // batch -> XCD (208 = 8*26)
  const int idx = blockIdx.x >> 3;   // 0..25
  int tm, tn, which; float wgt;
  if (idx < 16){ which = 1; tm = idx >> 2; tn = idx & 3; wgt = 1.f; }
  else {
    int e = idx - 16; which = 0;
    if      (e < 4){ tm = 0; tn = e;   }
    else if (e < 7){ tm = 1; tn = e-3; }
    else if (e < 9){ tm = 2; tn = e-5; }
    else           { tm = 3; tn = 3;   }
    wgt = (tm == tn) ? 1.f : 2.f;
  }
  const char* Ab = (which ? Tn : Sn) + (size_t)b*(NC*ROWB8) + (size_t)tm*(256*ROWB8);
  const char* Bb = Sn                + (size_t)b*(NC*ROWB8) + (size_t)tn*(256*ROWB8);

  const int scol = ((l & 7) << 4) ^ ((l >> 3) << 4);
  const char* gA = Ab + (8*w + (l >> 3))*ROWB8 + scol;
  const char* gB = Bb + (8*w + (l >> 3))*ROWB8 + scol;
  char* ldsw = lds + w*1024;

  const int swz = (l & 7) << 4;
  const int cg  = 32*(l >> 5);
  const int c00 = ( cg           ) ^ swz;
  const int c01 = ( cg | 16      ) ^ swz;
  const int c10 = ( cg | 64      ) ^ swz;
  const int c11 = ( cg | 64 | 16 ) ^ swz;
  const char* aRow = lds +         (wr*128 + (l & 31))*128;
  const char* bRow = lds + 32768 + (wc*64  + (l & 31))*128;

  i32x8 af[2][2], bf[2][2];
  f32x16 acc[8];
  #pragma unroll
  for (int i = 0; i < 8; i++) acc[i] = (f32x16){};

  ISSUE(1,0,0,0); ISSUE(1,0,1,0); ISSUE(0,0,0,0); ISSUE(0,0,1,0);
  ISSUE(1,1,0,1); ISSUE(1,1,1,1); ISSUE(0,1,0,1);
  VM6; BAR;   // oldest 8 loads (= all of t0) landed

  for (int i = 0; i < 12; i++){
    const int t1 = 2*i + 1;
    const int t2 = 2*i + 2;
    int t3 = 2*i + 3; if (t3 > 24) t3 = 24;   // clamp keeps vmcnt uniform

    // ---- tile 2i (buf0) ----
    RDA(0,0); RDB(0,0);
    ISSUE(0,1,1,t1);
    LGKM8; BAR; LGKM0; SB0; PRIO1; MMQ(0,0); PRIO0; BAR;
    RDB(0,1);
    BAR; LGKM0; SB0; PRIO1; MMQ(0,1); PRIO0; BAR;
    RDA(0,1);
    ISSUE(1,0,0,t2); ISSUE(1,0,1,t2);
    BAR; LGKM0; SB0; PRIO1; MMQ(1,0); PRIO0; BAR;
    ISSUE(0,0,0,t2);
    BAR; PRIO1; MMQ(1,1); PRIO0; VM6; BAR;

    // ---- tile 2i+1 (buf1) ----
    RDA(65536,0); RDB(65536,0);
    ISSUE(0,0,1,t2);
    LGKM8; BAR; LGKM0; SB0; PRIO1; MMQ(0,0); PRIO0; BAR;
    RDB(65536,1);
    BAR; LGKM0; SB0; PRIO1; MMQ(0,1); PRIO0; BAR;
    RDA(65536,1);
    ISSUE(1,1,0,t3); ISSUE(1,1,1,t3);
    BAR; LGKM0; SB0; PRIO1; MMQ(1,0); PRIO0; BAR;
    ISSUE(0,1,0,t3);
    BAR; PRIO1; MMQ(1,1); PRIO0; VM6; BAR;
  }

  // Epilogue: tile 24 (buf0), fully landed by final VM6+BAR.
  RDA(0,0); RDB(0,0); RDB(0,1);
  MMQ(0,0); MMQ(0,1);
  RDA(0,1);
  MMQ(1,0); MMQ(1,1);

  // Fused reduction: sum of squares of the 256x256 tile (layout-free).
  float p = 0.f;
  #pragma unroll
  for (int f = 0; f < 8; f++)
    #pragma unroll
    for (int e = 0; e < 16; e++)
      p = fmaf(acc[f][e], acc[f][e], p);
  #pragma unroll
  for (int off = 32; off; off >>= 1) p += __shfl_down(p, off);
  __syncthreads();
  float* red = (float*)lds;
  if (l == 0) red[w] = p;
  __syncthreads();
  if (tid == 0){
    float sum = red[0]+red[1]+red[2]+red[3]+red[4]+red[5]+red[6]+red[7];
    atomicAdd(&accbuf[which], wgt * sum);
  }
}

__global__ void k_fin(const float* __restrict__ acc, float* __restrict__ out){
  // / (8*1024*1024) and / 2^20 (both operands pre-scaled by 2^5)
  out[0] = (acc[0] - 2.0f*acc[1]) * 1.1368683772161603e-13f;   // 2^-43
}

extern "C" void kernel_launch(void* const* d_in, const int* in_sizes, int n_in,
                              void* d_out, int out_size, void* d_ws, size_t ws_size,
                              hipStream_t stream){
  const float* fs = (const float*)d_in[0];
  const float* ft = (const float*)d_in[1];
  float* out = (float*)d_out;
  float* accbuf = (float*)d_ws;
  char* Sn = (char*)d_ws + 256;
  char* Tn = Sn + (size_t)NB*NC*ROWB8;   // 2 x 26.2 MB of ws

  k_norm<<<dim3(16384), dim3(256), 0, stream>>>(fs, ft, Sn, Tn, accbuf);
  k_gemm<<<dim3(208), dim3(512), 0, stream>>>(Sn, Tn, accbuf);
  k_fin<<<1, 1, 0, stream>>>(accbuf, out);
}